// Round 1
// baseline (395.964 us; speedup 1.0000x reference)
//
#include <hip/hip_runtime.h>
#include <hip/hip_bf16.h>

// ---------------------------------------------------------------------------
// GQA block: y = Attn(x Wq + bq, x Wk + bk, x Wv + bv) Wo + bo
// B=2 S=2048 E=2048 H=16 G=4 D=128 R=4.  All GEMMs in bf16 MFMA, fp32 accum.
// ---------------------------------------------------------------------------

typedef __attribute__((ext_vector_type(8))) short bf16x8;
typedef __attribute__((ext_vector_type(4))) float f32x4;

#define MFMA_16x16x32(a, b, c) __builtin_amdgcn_mfma_f32_16x16x32_bf16((a), (b), (c), 0, 0, 0)

__device__ __forceinline__ unsigned short f2bf(float x) {
  union { float f; unsigned int u; } c;
  c.f = x;
  unsigned int u = c.u;
  return (unsigned short)((u + 0x7fffu + ((u >> 16) & 1u)) >> 16);  // RNE
}

__device__ __forceinline__ void gload_lds16(const void* g, void* l) {
  __builtin_amdgcn_global_load_lds(
      (const __attribute__((address_space(1))) unsigned int*)g,
      (__attribute__((address_space(3))) unsigned int*)l, 16, 0, 0);
}

// ---------------------------------------------------------------------------
// cast fp32 -> bf16, 8 elems/thread
__global__ void cast_x_kernel(const float* __restrict__ x,
                              unsigned short* __restrict__ out, long n) {
  long i = ((long)blockIdx.x * blockDim.x + threadIdx.x) * 8;
  if (i >= n) return;
  float4 a = *reinterpret_cast<const float4*>(x + i);
  float4 b = *reinterpret_cast<const float4*>(x + i + 4);
  union { unsigned short s[8]; bf16x8 v; } o;
  o.s[0] = f2bf(a.x); o.s[1] = f2bf(a.y); o.s[2] = f2bf(a.z); o.s[3] = f2bf(a.w);
  o.s[4] = f2bf(b.x); o.s[5] = f2bf(b.y); o.s[6] = f2bf(b.z); o.s[7] = f2bf(b.w);
  *reinterpret_cast<bf16x8*>(out + i) = o.v;
}

// transpose + cast: src fp32 [K][N] -> dst bf16 [N][K]
__global__ void transpose_cast_kernel(const float* __restrict__ src,
                                      unsigned short* __restrict__ dst,
                                      int K, int N) {
  __shared__ float t[32][33];
  const int tx = threadIdx.x, ty = threadIdx.y;
  const int n0 = blockIdx.x * 32, k0 = blockIdx.y * 32;
#pragma unroll
  for (int i = 0; i < 4; i++)
    t[ty + i * 8][tx] = src[(size_t)(k0 + ty + i * 8) * N + n0 + tx];
  __syncthreads();
#pragma unroll
  for (int i = 0; i < 4; i++)
    dst[(size_t)(n0 + ty + i * 8) * K + k0 + tx] = f2bf(t[tx][ty + i * 8]);
}

__global__ void concat_bias_kernel(const float* __restrict__ bq,
                                   const float* __restrict__ bk,
                                   const float* __restrict__ bv,
                                   float* __restrict__ out) {
  int i = blockIdx.x * 256 + threadIdx.x;
  if (i >= 3072) return;
  out[i] = (i < 2048) ? bq[i] : (i < 2560 ? bk[i - 2048] : bv[i - 2560]);
}

// ---------------------------------------------------------------------------
// C[m][n] = sum_k A[m][k] * Bt[n][k] + bias[n]   (A,Bt bf16; accum fp32)
// 128x128 tile, BK=32, 256 threads = 4 waves (2x2), global_load_lds staging.
template <bool BF16OUT>
__global__ __launch_bounds__(256, 2)
void gemm_bt_kernel(const unsigned short* __restrict__ A,
                    const unsigned short* __restrict__ Bt,
                    const float* __restrict__ bias,
                    void* __restrict__ C, int M, int N, int K) {
  __shared__ unsigned short Ash[128 * 32];
  __shared__ unsigned short Bsh[128 * 32];
  const int tid = threadIdx.x;
  const int w = tid >> 6, l = tid & 63, lg = l >> 4, ll = l & 15;
  const int wr = w >> 1, wc = w & 1;
  const int m0 = blockIdx.y * 128, n0 = blockIdx.x * 128;

  const f32x4 fz = {0.f, 0.f, 0.f, 0.f};
  f32x4 acc[4][4];
#pragma unroll
  for (int i = 0; i < 4; i++)
#pragma unroll
    for (int j = 0; j < 4; j++) acc[i][j] = fz;

  const size_t arow0 = (size_t)(m0 + (tid >> 2)) * K + (tid & 3) * 8;
  const size_t brow0 = (size_t)(n0 + (tid >> 2)) * K + (tid & 3) * 8;
  unsigned short* adst = &Ash[w * 512];
  unsigned short* bdst = &Bsh[w * 512];

  for (int k0 = 0; k0 < K; k0 += 32) {
    gload_lds16(A + arow0 + k0, adst);
    gload_lds16(A + arow0 + (size_t)64 * K + k0, adst + 2048);
    gload_lds16(Bt + brow0 + k0, bdst);
    gload_lds16(Bt + brow0 + (size_t)64 * K + k0, bdst + 2048);
    __syncthreads();
    bf16x8 af[4], bfr[4];
#pragma unroll
    for (int mi = 0; mi < 4; mi++)
      af[mi] = *reinterpret_cast<const bf16x8*>(&Ash[(wr * 64 + mi * 16 + ll) * 32 + 8 * lg]);
#pragma unroll
    for (int ni = 0; ni < 4; ni++)
      bfr[ni] = *reinterpret_cast<const bf16x8*>(&Bsh[(wc * 64 + ni * 16 + ll) * 32 + 8 * lg]);
#pragma unroll
    for (int mi = 0; mi < 4; mi++)
#pragma unroll
      for (int ni = 0; ni < 4; ni++)
        acc[mi][ni] = MFMA_16x16x32(af[mi], bfr[ni], acc[mi][ni]);
    __syncthreads();
  }

#pragma unroll
  for (int mi = 0; mi < 4; mi++) {
#pragma unroll
    for (int ni = 0; ni < 4; ni++) {
      const int gc = n0 + wc * 64 + ni * 16 + ll;
      const float bv = bias[gc];
#pragma unroll
      for (int r = 0; r < 4; r++) {
        const int gr = m0 + wr * 64 + mi * 16 + 4 * lg + r;
        const float v = acc[mi][ni][r] + bv;
        if (BF16OUT)
          ((unsigned short*)C)[(size_t)gr * N + gc] = f2bf(v);
        else
          ((float*)C)[(size_t)gr * N + gc] = v;
      }
    }
  }
}

// ---------------------------------------------------------------------------
// Flash attention. QKV: [4096][3072] bf16 (Q cols 0..2047 = h*128+d,
// K cols 2048+g*128+d, V cols 2560+g*128+d). AO: [4096][2048] bf16.
// Block: 256 thr = 4 waves, each wave 32 q-rows; KV tile = 64.
__global__ __launch_bounds__(256, 2)
void attn_kernel(const unsigned short* __restrict__ QKV,
                 unsigned short* __restrict__ AO) {
  __shared__ unsigned short Klds[64 * 128];   // [kv][d], byte ^ ((kv&7)<<4)
  __shared__ unsigned short Vtlds[128 * 64];  // [d][kv], byte ^ (((d>>3)&7)<<4)
  __shared__ unsigned short Plds[4][32 * 64]; // per-wave [q][kv], byte ^ ((q&7)<<4)

  const int tid = threadIdx.x;
  const int w = tid >> 6, l = tid & 63, lg = l >> 4, ll = l & 15;
  const int bh = blockIdx.y;
  const int b = bh >> 4, h = bh & 15, g = h >> 2;
  const int q0 = blockIdx.x * 128 + w * 32;
  const size_t row_base = (size_t)b * 2048 * 3072;

  // hoist Q fragments (A operand): rows q0+mi*16+ll, k-slots d = ds*32+8*lg..
  bf16x8 qf[2][4];
#pragma unroll
  for (int mi = 0; mi < 2; mi++)
#pragma unroll
    for (int ds = 0; ds < 4; ds++)
      qf[mi][ds] = *reinterpret_cast<const bf16x8*>(
          QKV + row_base + (size_t)(q0 + mi * 16 + ll) * 3072 + h * 128 + ds * 32 + 8 * lg);

  const f32x4 fz = {0.f, 0.f, 0.f, 0.f};
  f32x4 o[2][8];
#pragma unroll
  for (int mi = 0; mi < 2; mi++)
#pragma unroll
    for (int di = 0; di < 8; di++) o[mi][di] = fz;
  float mrow[2][4], lrow[2][4];
#pragma unroll
  for (int mi = 0; mi < 2; mi++)
#pragma unroll
    for (int r = 0; r < 4; r++) { mrow[mi][r] = -3.0e38f; lrow[mi][r] = 0.f; }

  const float SCALE = 0.08838834764831845f;  // 1/sqrt(128)
  const int kv_lane = tid >> 4;              // 0..15
  const int d0 = (tid & 15) * 8;

  for (int kt = 0; kt < 32; kt++) {
    // ---- stage K and V^T tiles ----
#pragma unroll
    for (int i = 0; i < 4; i++) {
      const int kv = i * 16 + kv_lane;
      const size_t grow = row_base + (size_t)(kt * 64 + kv) * 3072 + g * 128 + d0;
      bf16x8 kvec = *reinterpret_cast<const bf16x8*>(QKV + grow + 2048);
      const int kidx = (kv * 128 + d0) ^ ((kv & 7) << 3);
      *reinterpret_cast<bf16x8*>(&Klds[kidx]) = kvec;
      bf16x8 vvec = *reinterpret_cast<const bf16x8*>(QKV + grow + 2560);
#pragma unroll
      for (int j = 0; j < 8; j++) {
        const int d = d0 + j;
        Vtlds[(d * 64 + kv) ^ (((d >> 3) & 7) << 3)] = (unsigned short)vvec[j];
      }
    }
    __syncthreads();

    // ---- S = Q K^T ----
    f32x4 s[2][4];
#pragma unroll
    for (int mi = 0; mi < 2; mi++)
#pragma unroll
      for (int ni = 0; ni < 4; ni++) s[mi][ni] = fz;
#pragma unroll
    for (int ds = 0; ds < 4; ds++) {
      bf16x8 kf[4];
#pragma unroll
      for (int ni = 0; ni < 4; ni++) {
        const int kv = ni * 16 + ll;
        const int idx = (kv * 128 + ds * 32 + 8 * lg) ^ ((kv & 7) << 3);
        kf[ni] = *reinterpret_cast<const bf16x8*>(&Klds[idx]);
      }
#pragma unroll
      for (int mi = 0; mi < 2; mi++)
#pragma unroll
        for (int ni = 0; ni < 4; ni++)
          s[mi][ni] = MFMA_16x16x32(qf[mi][ds], kf[ni], s[mi][ni]);
    }

    // ---- online softmax ----
    float pm[2][4];
#pragma unroll
    for (int mi = 0; mi < 2; mi++)
#pragma unroll
      for (int r = 0; r < 4; r++)
        pm[mi][r] = fmaxf(fmaxf(s[mi][0][r], s[mi][1][r]),
                          fmaxf(s[mi][2][r], s[mi][3][r]));
#pragma unroll
    for (int off = 1; off < 16; off <<= 1)
#pragma unroll
      for (int mi = 0; mi < 2; mi++)
#pragma unroll
        for (int r = 0; r < 4; r++)
          pm[mi][r] = fmaxf(pm[mi][r], __shfl_xor(pm[mi][r], off, 64));

    float fac[2][4], psum[2][4];
#pragma unroll
    for (int mi = 0; mi < 2; mi++)
#pragma unroll
      for (int r = 0; r < 4; r++) {
        const float mn = fmaxf(mrow[mi][r], pm[mi][r] * SCALE);
        fac[mi][r] = __expf(mrow[mi][r] - mn);
        mrow[mi][r] = mn;
        psum[mi][r] = 0.f;
      }
#pragma unroll
    for (int mi = 0; mi < 2; mi++)
#pragma unroll
      for (int ni = 0; ni < 4; ni++)
#pragma unroll
        for (int r = 0; r < 4; r++) {
          const float p = __expf(s[mi][ni][r] * SCALE - mrow[mi][r]);
          psum[mi][r] += p;
          const int q = mi * 16 + 4 * lg + r;
          const int kv = ni * 16 + ll;
          Plds[w][(q * 64 + kv) ^ ((q & 7) << 3)] = f2bf(p);
        }
#pragma unroll
    for (int off = 1; off < 16; off <<= 1)
#pragma unroll
      for (int mi = 0; mi < 2; mi++)
#pragma unroll
        for (int r = 0; r < 4; r++)
          psum[mi][r] += __shfl_xor(psum[mi][r], off, 64);
#pragma unroll
    for (int mi = 0; mi < 2; mi++)
#pragma unroll
      for (int r = 0; r < 4; r++)
        lrow[mi][r] = lrow[mi][r] * fac[mi][r] + psum[mi][r];
#pragma unroll
    for (int mi = 0; mi < 2; mi++)
#pragma unroll
      for (int di = 0; di < 8; di++)
#pragma unroll
        for (int r = 0; r < 4; r++) o[mi][di][r] *= fac[mi][r];

    // ---- O += P V ----
#pragma unroll
    for (int ks = 0; ks < 2; ks++) {
      bf16x8 pf[2];
#pragma unroll
      for (int mi = 0; mi < 2; mi++) {
        const int q = mi * 16 + ll;
        const int idx = (q * 64 + ks * 32 + 8 * lg) ^ ((q & 7) << 3);
        pf[mi] = *reinterpret_cast<const bf16x8*>(&Plds[w][idx]);
      }
#pragma unroll
      for (int di = 0; di < 8; di++) {
        const int d = di * 16 + ll;
        const int idx = (d * 64 + ks * 32 + 8 * lg) ^ (((d >> 3) & 7) << 3);
        const bf16x8 vf = *reinterpret_cast<const bf16x8*>(&Vtlds[idx]);
#pragma unroll
        for (int mi = 0; mi < 2; mi++)
          o[mi][di] = MFMA_16x16x32(pf[mi], vf, o[mi][di]);
      }
    }
    __syncthreads();
  }

  // ---- epilogue: normalize, write AO[b*2048+q][h*128+d] ----
#pragma unroll
  for (int mi = 0; mi < 2; mi++)
#pragma unroll
    for (int di = 0; di < 8; di++) {
      const int col = h * 128 + di * 16 + ll;
#pragma unroll
      for (int r = 0; r < 4; r++) {
        const int qr = q0 + mi * 16 + 4 * lg + r;
        AO[(size_t)(b * 2048 + qr) * 2048 + col] = f2bf(o[mi][di][r] / lrow[mi][r]);
      }
    }
}

// ---------------------------------------------------------------------------
extern "C" void kernel_launch(void* const* d_in, const int* in_sizes, int n_in,
                              void* d_out, int out_size, void* d_ws, size_t ws_size,
                              hipStream_t stream) {
  const float* x  = (const float*)d_in[0];
  const float* Wq = (const float*)d_in[1];
  const float* bq = (const float*)d_in[2];
  const float* Wk = (const float*)d_in[3];
  const float* bk = (const float*)d_in[4];
  const float* Wv = (const float*)d_in[5];
  const float* bv = (const float*)d_in[6];
  const float* Wo = (const float*)d_in[7];
  const float* bo = (const float*)d_in[8];
  float* out = (float*)d_out;

  // workspace carve (bf16 elems):
  unsigned short* xb    = (unsigned short*)d_ws;               // 4096*2048
  unsigned short* WqkvT = xb + (size_t)4096 * 2048;            // 3072*2048
  unsigned short* WoT   = WqkvT + (size_t)3072 * 2048;         // 2048*2048
  unsigned short* QKV   = WoT + (size_t)2048 * 2048;           // 4096*3072
  unsigned short* AO    = QKV + (size_t)4096 * 3072;           // 4096*2048
  float* bqkv = (float*)(AO + (size_t)4096 * 2048);            // 3072 f32

  cast_x_kernel<<<4096, 256, 0, stream>>>(x, xb, (long)8388608);
  transpose_cast_kernel<<<dim3(64, 64), dim3(32, 8), 0, stream>>>(Wq, WqkvT, 2048, 2048);
  transpose_cast_kernel<<<dim3(16, 64), dim3(32, 8), 0, stream>>>(Wk, WqkvT + (size_t)2048 * 2048, 2048, 512);
  transpose_cast_kernel<<<dim3(16, 64), dim3(32, 8), 0, stream>>>(Wv, WqkvT + (size_t)2560 * 2048, 2048, 512);
  transpose_cast_kernel<<<dim3(64, 64), dim3(32, 8), 0, stream>>>(Wo, WoT, 2048, 2048);
  concat_bias_kernel<<<12, 256, 0, stream>>>(bq, bk, bv, bqkv);

  // QKV = xb @ WqkvT^T + bqkv  -> bf16 [4096][3072]
  gemm_bt_kernel<true><<<dim3(24, 32), 256, 0, stream>>>(xb, WqkvT, bqkv, QKV, 4096, 3072, 2048);
  // flash attention -> AO bf16 [4096][2048]
  attn_kernel<<<dim3(16, 32), 256, 0, stream>>>(QKV, AO);
  // out = AO @ WoT^T + bo -> fp32
  gemm_bt_kernel<false><<<dim3(16, 32), 256, 0, stream>>>(AO, WoT, bo, out, 4096, 2048, 2048);
}

// Round 2
// 226.159 us; speedup vs baseline: 1.7508x; 1.7508x over previous
//
#include <hip/hip_runtime.h>
#include <hip/hip_bf16.h>

// ---------------------------------------------------------------------------
// GQA block: y = Attn(x Wq + bq, x Wk + bk, x Wv + bv) Wo + bo
// B=2 S=2048 E=2048 H=16 G=4 D=128 R=4.  All GEMMs in bf16 MFMA, fp32 accum.
// R1: swapped QK^T attention (P in-register), V pre-transpose, T14 staging,
//     defer-max, scale folded into Q.
// ---------------------------------------------------------------------------

typedef __attribute__((ext_vector_type(8))) short bf16x8;
typedef __attribute__((ext_vector_type(4))) short bf16x4;
typedef __attribute__((ext_vector_type(4))) float f32x4;

#define MFMA_16x16x32(a, b, c) __builtin_amdgcn_mfma_f32_16x16x32_bf16((a), (b), (c), 0, 0, 0)

__device__ __forceinline__ unsigned short f2bf(float x) {
  union { float f; unsigned int u; } c;
  c.f = x;
  unsigned int u = c.u;
  return (unsigned short)((u + 0x7fffu + ((u >> 16) & 1u)) >> 16);  // RNE
}

__device__ __forceinline__ void gload_lds16(const void* g, void* l) {
  __builtin_amdgcn_global_load_lds(
      (const __attribute__((address_space(1))) unsigned int*)g,
      (__attribute__((address_space(3))) unsigned int*)l, 16, 0, 0);
}

// ---------------------------------------------------------------------------
// cast fp32 -> bf16, 8 elems/thread
__global__ void cast_x_kernel(const float* __restrict__ x,
                              unsigned short* __restrict__ out, long n) {
  long i = ((long)blockIdx.x * blockDim.x + threadIdx.x) * 8;
  if (i >= n) return;
  float4 a = *reinterpret_cast<const float4*>(x + i);
  float4 b = *reinterpret_cast<const float4*>(x + i + 4);
  union { unsigned short s[8]; bf16x8 v; } o;
  o.s[0] = f2bf(a.x); o.s[1] = f2bf(a.y); o.s[2] = f2bf(a.z); o.s[3] = f2bf(a.w);
  o.s[4] = f2bf(b.x); o.s[5] = f2bf(b.y); o.s[6] = f2bf(b.z); o.s[7] = f2bf(b.w);
  *reinterpret_cast<bf16x8*>(out + i) = o.v;
}

// transpose + cast: src fp32 [K][N] -> dst bf16 [N][K]
__global__ void transpose_cast_kernel(const float* __restrict__ src,
                                      unsigned short* __restrict__ dst,
                                      int K, int N) {
  __shared__ float t[32][33];
  const int tx = threadIdx.x, ty = threadIdx.y;
  const int n0 = blockIdx.x * 32, k0 = blockIdx.y * 32;
#pragma unroll
  for (int i = 0; i < 4; i++)
    t[ty + i * 8][tx] = src[(size_t)(k0 + ty + i * 8) * N + n0 + tx];
  __syncthreads();
#pragma unroll
  for (int i = 0; i < 4; i++)
    dst[(size_t)(n0 + ty + i * 8) * K + k0 + tx] = f2bf(t[tx][ty + i * 8]);
}

__global__ void concat_bias_kernel(const float* __restrict__ bq,
                                   const float* __restrict__ bk,
                                   const float* __restrict__ bv,
                                   float* __restrict__ out) {
  int i = blockIdx.x * 256 + threadIdx.x;
  if (i >= 3072) return;
  out[i] = (i < 2048) ? bq[i] : (i < 2560 ? bk[i - 2048] : bv[i - 2560]);
}

// V region of QKV -> Vt[b*512 + g*128 + d][2048 s], with kv-permutation c()
// within each 64-block of s:  c = ((s&12)<<1) | (((s>>4)&1)<<2) | (s&3) | (s&32)
__global__ void transpose_v_kernel(const unsigned short* __restrict__ QKV,
                                   unsigned short* __restrict__ Vt) {
  __shared__ unsigned short t[32][33];
  const int tx = threadIdx.x, ty = threadIdx.y;
  const int c0 = blockIdx.x * 32;  // gd
  const int r0 = blockIdx.y * 32;  // b*2048+s
#pragma unroll
  for (int i = 0; i < 4; i++)
    t[ty + i * 8][tx] = QKV[(size_t)(r0 + ty + i * 8) * 3072 + 2560 + c0 + tx];
  __syncthreads();
#pragma unroll
  for (int i = 0; i < 4; i++) {
    const int gd = c0 + ty + i * 8;
    const int r = r0 + tx;
    const int b = r >> 11, s = r & 2047;
    const int sp = (s & ~63) | ((s & 12) << 1) | (((s >> 4) & 1) << 2) | (s & 3) | (s & 32);
    Vt[(size_t)(b * 512 + gd) * 2048 + sp] = t[tx][ty + i * 8];
  }
}

// ---------------------------------------------------------------------------
// C[m][n] = (sum_k A[m][k]*Bt[n][k] + bias[n]) * (n<qcols ? qscale : 1)
template <bool BF16OUT>
__global__ __launch_bounds__(256, 2)
void gemm_bt_kernel(const unsigned short* __restrict__ A,
                    const unsigned short* __restrict__ Bt,
                    const float* __restrict__ bias,
                    void* __restrict__ C, int M, int N, int K,
                    float qscale, int qcols) {
  __shared__ unsigned short Ash[128 * 32];
  __shared__ unsigned short Bsh[128 * 32];
  const int tid = threadIdx.x;
  const int w = tid >> 6, l = tid & 63, lg = l >> 4, ll = l & 15;
  const int wr = w >> 1, wc = w & 1;
  const int m0 = blockIdx.y * 128, n0 = blockIdx.x * 128;

  const f32x4 fz = {0.f, 0.f, 0.f, 0.f};
  f32x4 acc[4][4];
#pragma unroll
  for (int i = 0; i < 4; i++)
#pragma unroll
    for (int j = 0; j < 4; j++) acc[i][j] = fz;

  const size_t arow0 = (size_t)(m0 + (tid >> 2)) * K + (tid & 3) * 8;
  const size_t brow0 = (size_t)(n0 + (tid >> 2)) * K + (tid & 3) * 8;
  unsigned short* adst = &Ash[w * 512];
  unsigned short* bdst = &Bsh[w * 512];

  for (int k0 = 0; k0 < K; k0 += 32) {
    gload_lds16(A + arow0 + k0, adst);
    gload_lds16(A + arow0 + (size_t)64 * K + k0, adst + 2048);
    gload_lds16(Bt + brow0 + k0, bdst);
    gload_lds16(Bt + brow0 + (size_t)64 * K + k0, bdst + 2048);
    __syncthreads();
    bf16x8 af[4], bfr[4];
#pragma unroll
    for (int mi = 0; mi < 4; mi++)
      af[mi] = *reinterpret_cast<const bf16x8*>(&Ash[(wr * 64 + mi * 16 + ll) * 32 + 8 * lg]);
#pragma unroll
    for (int ni = 0; ni < 4; ni++)
      bfr[ni] = *reinterpret_cast<const bf16x8*>(&Bsh[(wc * 64 + ni * 16 + ll) * 32 + 8 * lg]);
#pragma unroll
    for (int mi = 0; mi < 4; mi++)
#pragma unroll
      for (int ni = 0; ni < 4; ni++)
        acc[mi][ni] = MFMA_16x16x32(af[mi], bfr[ni], acc[mi][ni]);
    __syncthreads();
  }

#pragma unroll
  for (int mi = 0; mi < 4; mi++) {
#pragma unroll
    for (int ni = 0; ni < 4; ni++) {
      const int gc = n0 + wc * 64 + ni * 16 + ll;
      const float bv = bias[gc];
      const float sc = (gc < qcols) ? qscale : 1.0f;
#pragma unroll
      for (int r = 0; r < 4; r++) {
        const int gr = m0 + wr * 64 + mi * 16 + 4 * lg + r;
        const float v = (acc[mi][ni][r] + bv) * sc;
        if (BF16OUT)
          ((unsigned short*)C)[(size_t)gr * N + gc] = f2bf(v);
        else
          ((float*)C)[(size_t)gr * N + gc] = v;
      }
    }
  }
}

// ---------------------------------------------------------------------------
// Flash attention, swapped-QK^T structure.
// QKV: [4096][3072] bf16; Q cols (h*128+d) are pre-scaled by 1/sqrt(D)*log2(e).
// Vt: [1024][2048] bf16 = V^T per (b,g), kv-permuted via c().
// Block: 256 thr = 4 waves, each wave 32 q-rows; KV tile = 64; 32 kv-tiles.
__global__ __launch_bounds__(256, 2)
void attn_kernel(const unsigned short* __restrict__ QKV,
                 const unsigned short* __restrict__ Vt,
                 unsigned short* __restrict__ AO) {
  __shared__ unsigned short Klds[64 * 128];  // [kv][d]   elem ^ ((kv&7)<<3)
  __shared__ unsigned short Vlds[128 * 64];  // [d][c]    elem ^ ((d&7)<<3)

  const int tid = threadIdx.x;
  const int w = tid >> 6, l = tid & 63, lg = l >> 4, ll = l & 15;
  const int bh = blockIdx.y;
  const int b = bh >> 4, h = bh & 15, g = h >> 2;
  const int q0 = blockIdx.x * 128 + w * 32;
  const size_t row_base = (size_t)b * 2048 * 3072;
  const unsigned short* Vg = Vt + (size_t)(b * 512 + g * 128) * 2048;

  // hoisted Q fragments (B operand): lane ll <-> q = q0+mi*16+ll
  bf16x8 qf[2][4];
#pragma unroll
  for (int mi = 0; mi < 2; mi++)
#pragma unroll
    for (int ds = 0; ds < 4; ds++)
      qf[mi][ds] = *reinterpret_cast<const bf16x8*>(
          QKV + row_base + (size_t)(q0 + mi * 16 + ll) * 3072 + h * 128 + ds * 32 + 8 * lg);

  const f32x4 fz = {0.f, 0.f, 0.f, 0.f};
  f32x4 o[8][2];  // O^T accum: o[di][mi], lane holds d=di*16+4lg+r, q=mi*16+ll
#pragma unroll
  for (int di = 0; di < 8; di++)
#pragma unroll
    for (int mi = 0; mi < 2; mi++) o[di][mi] = fz;
  float m2[2] = {-3.0e38f, -3.0e38f}, lsum[2] = {0.f, 0.f};

  // staging maps (4 x 16B each for K and V per thread)
  const int krow = tid >> 4, kc8 = tid & 15;   // K rows krow+16i
  const int vrow = tid >> 3, vc8 = tid & 7;    // V rows vrow+32i
  const unsigned short* Kg = QKV + row_base + 2048 + g * 128 + kc8 * 8 + (size_t)krow * 3072;
  int klo[4], vlo[4];
#pragma unroll
  for (int i = 0; i < 4; i++) {
    const int kr = krow + 16 * i;
    klo[i] = (kr * 128 + kc8 * 8) ^ ((kr & 7) << 3);
    const int vr = vrow + 32 * i;
    vlo[i] = (vr * 64 + vc8 * 8) ^ ((vr & 7) << 3);
  }

  bf16x8 kreg[4], vreg[4];
#pragma unroll
  for (int i = 0; i < 4; i++) {
    kreg[i] = *reinterpret_cast<const bf16x8*>(Kg + (size_t)(16 * i) * 3072);
    vreg[i] = *reinterpret_cast<const bf16x8*>(Vg + (size_t)(vrow + 32 * i) * 2048 + vc8 * 8);
  }

  const float THR = 8.0f;

  for (int kt = 0; kt < 32; kt++) {
    // ---- write staged tile ----
#pragma unroll
    for (int i = 0; i < 4; i++) *reinterpret_cast<bf16x8*>(&Klds[klo[i]]) = kreg[i];
#pragma unroll
    for (int i = 0; i < 4; i++) *reinterpret_cast<bf16x8*>(&Vlds[vlo[i]]) = vreg[i];
    __syncthreads();

    // ---- issue next-tile loads (latency hidden under compute) ----
    if (kt + 1 < 32) {
#pragma unroll
      for (int i = 0; i < 4; i++) {
        kreg[i] = *reinterpret_cast<const bf16x8*>(
            Kg + (size_t)((kt + 1) * 64 + 16 * i) * 3072);
        vreg[i] = *reinterpret_cast<const bf16x8*>(
            Vg + (size_t)(vrow + 32 * i) * 2048 + (kt + 1) * 64 + vc8 * 8);
      }
    }

    // ---- S^T = K Q^T : st[ni][mi], lane = (kv=ni*16+4lg+r, q=mi*16+ll) ----
    f32x4 st[4][2];
#pragma unroll
    for (int ni = 0; ni < 4; ni++)
#pragma unroll
      for (int mi = 0; mi < 2; mi++) st[ni][mi] = fz;
#pragma unroll
    for (int ds = 0; ds < 4; ds++) {
      bf16x8 kf[4];
#pragma unroll
      for (int ni = 0; ni < 4; ni++) {
        const int kr = ni * 16 + ll;
        kf[ni] = *reinterpret_cast<const bf16x8*>(
            &Klds[(kr * 128 + ds * 32 + 8 * lg) ^ ((kr & 7) << 3)]);
      }
#pragma unroll
      for (int ni = 0; ni < 4; ni++)
#pragma unroll
        for (int mi = 0; mi < 2; mi++)
          st[ni][mi] = MFMA_16x16x32(kf[ni], qf[mi][ds], st[ni][mi]);
    }

    // ---- online softmax (log2 domain; scores already * 1/sqrt(D)*log2e) ----
    float pm[2];
#pragma unroll
    for (int mi = 0; mi < 2; mi++) {
      float a0 = fmaxf(fmaxf(st[0][mi][0], st[0][mi][1]), fmaxf(st[0][mi][2], st[0][mi][3]));
      float a1 = fmaxf(fmaxf(st[1][mi][0], st[1][mi][1]), fmaxf(st[1][mi][2], st[1][mi][3]));
      float a2 = fmaxf(fmaxf(st[2][mi][0], st[2][mi][1]), fmaxf(st[2][mi][2], st[2][mi][3]));
      float a3 = fmaxf(fmaxf(st[3][mi][0], st[3][mi][1]), fmaxf(st[3][mi][2], st[3][mi][3]));
      pm[mi] = fmaxf(fmaxf(a0, a1), fmaxf(a2, a3));
      pm[mi] = fmaxf(pm[mi], __shfl_xor(pm[mi], 16, 64));
      pm[mi] = fmaxf(pm[mi], __shfl_xor(pm[mi], 32, 64));
    }
    const bool grow = (pm[0] > m2[0] + THR) || (pm[1] > m2[1] + THR);
    if (__any(grow)) {
#pragma unroll
      for (int mi = 0; mi < 2; mi++) {
        const float mn = fmaxf(m2[mi], pm[mi]);
        const float fac = __builtin_amdgcn_exp2f(m2[mi] - mn);
        m2[mi] = mn;
        lsum[mi] *= fac;
#pragma unroll
        for (int di = 0; di < 8; di++) o[di][mi] *= fac;
      }
    }
    float ps[2] = {0.f, 0.f};
#pragma unroll
    for (int ni = 0; ni < 4; ni++)
#pragma unroll
      for (int mi = 0; mi < 2; mi++)
#pragma unroll
        for (int r = 0; r < 4; r++) {
          const float pv = __builtin_amdgcn_exp2f(st[ni][mi][r] - m2[mi]);
          st[ni][mi][r] = pv;
          ps[mi] += pv;
        }
#pragma unroll
    for (int mi = 0; mi < 2; mi++) {
      ps[mi] += __shfl_xor(ps[mi], 16, 64);
      ps[mi] += __shfl_xor(ps[mi], 32, 64);
      lsum[mi] += ps[mi];
    }

    // ---- pack P^T into B-operand slots (kv-slot (lg,j) fixed by C/D layout) ----
    bf16x8 pf[2][2];
#pragma unroll
    for (int mi = 0; mi < 2; mi++)
#pragma unroll
      for (int ks = 0; ks < 2; ks++)
#pragma unroll
        for (int j = 0; j < 4; j++) {
          pf[mi][ks][j]     = (short)f2bf(st[2 * ks][mi][j]);
          pf[mi][ks][4 + j] = (short)f2bf(st[2 * ks + 1][mi][j]);
        }

    // ---- O^T += V^T P^T ----
#pragma unroll
    for (int ks = 0; ks < 2; ks++)
#pragma unroll
      for (int di = 0; di < 8; di++) {
        const int dr = di * 16 + ll;
        const bf16x8 vf = *reinterpret_cast<const bf16x8*>(
            &Vlds[(dr * 64 + ks * 32 + 8 * lg) ^ ((dr & 7) << 3)]);
#pragma unroll
        for (int mi = 0; mi < 2; mi++)
          o[di][mi] = MFMA_16x16x32(vf, pf[mi][ks], o[di][mi]);
      }
    __syncthreads();
  }

  // ---- epilogue: O^T/lsum -> AO[b*2048+q][h*128+d], 4 contiguous d packed ----
  float invl[2];
#pragma unroll
  for (int mi = 0; mi < 2; mi++) invl[mi] = 1.0f / lsum[mi];
#pragma unroll
  for (int mi = 0; mi < 2; mi++) {
    const size_t rowoff = (size_t)(b * 2048 + q0 + mi * 16 + ll) * 2048 + h * 128;
#pragma unroll
    for (int di = 0; di < 8; di++) {
      union { unsigned short s[4]; bf16x4 v; } ov;
#pragma unroll
      for (int r = 0; r < 4; r++) ov.s[r] = f2bf(o[di][mi][r] * invl[mi]);
      *reinterpret_cast<bf16x4*>(&AO[rowoff + di * 16 + 4 * lg]) = ov.v;
    }
  }
}

// ---------------------------------------------------------------------------
extern "C" void kernel_launch(void* const* d_in, const int* in_sizes, int n_in,
                              void* d_out, int out_size, void* d_ws, size_t ws_size,
                              hipStream_t stream) {
  const float* x  = (const float*)d_in[0];
  const float* Wq = (const float*)d_in[1];
  const float* bq = (const float*)d_in[2];
  const float* Wk = (const float*)d_in[3];
  const float* bk = (const float*)d_in[4];
  const float* Wv = (const float*)d_in[5];
  const float* bv = (const float*)d_in[6];
  const float* Wo = (const float*)d_in[7];
  const float* bo = (const float*)d_in[8];
  float* out = (float*)d_out;

  // workspace carve (bf16 elems):
  unsigned short* xb    = (unsigned short*)d_ws;               // 4096*2048
  unsigned short* Vt    = xb;                                   // alias: xb dead after QKV GEMM
  unsigned short* WqkvT = xb + (size_t)4096 * 2048;            // 3072*2048
  unsigned short* WoT   = WqkvT + (size_t)3072 * 2048;         // 2048*2048
  unsigned short* QKV   = WoT + (size_t)2048 * 2048;           // 4096*3072
  unsigned short* AO    = QKV + (size_t)4096 * 3072;           // 4096*2048
  float* bqkv = (float*)(AO + (size_t)4096 * 2048);            // 3072 f32

  const float QSC2 = 0.08838834764831845f * 1.4426950408889634f;  // 1/sqrt(D)*log2e

  cast_x_kernel<<<4096, 256, 0, stream>>>(x, xb, (long)8388608);
  transpose_cast_kernel<<<dim3(64, 64), dim3(32, 8), 0, stream>>>(Wq, WqkvT, 2048, 2048);
  transpose_cast_kernel<<<dim3(16, 64), dim3(32, 8), 0, stream>>>(Wk, WqkvT + (size_t)2048 * 2048, 2048, 512);
  transpose_cast_kernel<<<dim3(16, 64), dim3(32, 8), 0, stream>>>(Wv, WqkvT + (size_t)2560 * 2048, 2048, 512);
  transpose_cast_kernel<<<dim3(64, 64), dim3(32, 8), 0, stream>>>(Wo, WoT, 2048, 2048);
  concat_bias_kernel<<<12, 256, 0, stream>>>(bq, bk, bv, bqkv);

  // QKV = xb @ WqkvT^T + bqkv; Q columns pre-scaled by QSC2 -> bf16 [4096][3072]
  gemm_bt_kernel<true><<<dim3(24, 32), 256, 0, stream>>>(xb, WqkvT, bqkv, QKV, 4096, 3072, 2048, QSC2, 2048);
  // V^T (kv-permuted) -> Vt [1024][2048]  (overwrites xb, now dead)
  transpose_v_kernel<<<dim3(16, 128), dim3(32, 8), 0, stream>>>(QKV, Vt);
  // flash attention -> AO bf16 [4096][2048]
  attn_kernel<<<dim3(16, 32), 256, 0, stream>>>(QKV, Vt, AO);
  // out = AO @ WoT^T + bo -> fp32
  gemm_bt_kernel<false><<<dim3(16, 32), 256, 0, stream>>>(AO, WoT, bo, out, 4096, 2048, 2048, 1.0f, 0);
}

// Round 3
// 215.498 us; speedup vs baseline: 1.8374x; 1.0495x over previous
//
#include <hip/hip_runtime.h>
#include <hip/hip_bf16.h>

// ---------------------------------------------------------------------------
// GQA block: y = Attn(x Wq + bq, x Wk + bk, x Wv + bv) Wo + bo
// B=2 S=2048 E=2048 H=16 G=4 D=128 R=4.  All GEMMs in bf16 MFMA, fp32 accum.
// R1: swapped QK^T attention (P in-register), V pre-transpose, T14 staging,
//     defer-max, scale folded into Q.
// R2: GEMMs -> 256-wide tile, 8-wave, 4-deep LDS ring, counted vmcnt (T3+T4),
//     raw s_barrier (no drain), setprio (T5). BK=32 keeps LDS conflict-free.
// ---------------------------------------------------------------------------

typedef __attribute__((ext_vector_type(8))) short bf16x8;
typedef __attribute__((ext_vector_type(4))) short bf16x4;
typedef __attribute__((ext_vector_type(4))) float f32x4;

#define MFMA_16x16x32(a, b, c) __builtin_amdgcn_mfma_f32_16x16x32_bf16((a), (b), (c), 0, 0, 0)

__device__ __forceinline__ unsigned short f2bf(float x) {
  union { float f; unsigned int u; } c;
  c.f = x;
  unsigned int u = c.u;
  return (unsigned short)((u + 0x7fffu + ((u >> 16) & 1u)) >> 16);  // RNE
}

__device__ __forceinline__ void gload_lds16(const void* g, void* l) {
  __builtin_amdgcn_global_load_lds(
      (const __attribute__((address_space(1))) unsigned int*)g,
      (__attribute__((address_space(3))) unsigned int*)l, 16, 0, 0);
}

// ---------------------------------------------------------------------------
// cast fp32 -> bf16, 8 elems/thread
__global__ void cast_x_kernel(const float* __restrict__ x,
                              unsigned short* __restrict__ out, long n) {
  long i = ((long)blockIdx.x * blockDim.x + threadIdx.x) * 8;
  if (i >= n) return;
  float4 a = *reinterpret_cast<const float4*>(x + i);
  float4 b = *reinterpret_cast<const float4*>(x + i + 4);
  union { unsigned short s[8]; bf16x8 v; } o;
  o.s[0] = f2bf(a.x); o.s[1] = f2bf(a.y); o.s[2] = f2bf(a.z); o.s[3] = f2bf(a.w);
  o.s[4] = f2bf(b.x); o.s[5] = f2bf(b.y); o.s[6] = f2bf(b.z); o.s[7] = f2bf(b.w);
  *reinterpret_cast<bf16x8*>(out + i) = o.v;
}

// transpose + cast: src fp32 [K][N] -> dst bf16 [N][K]
__global__ void transpose_cast_kernel(const float* __restrict__ src,
                                      unsigned short* __restrict__ dst,
                                      int K, int N) {
  __shared__ float t[32][33];
  const int tx = threadIdx.x, ty = threadIdx.y;
  const int n0 = blockIdx.x * 32, k0 = blockIdx.y * 32;
#pragma unroll
  for (int i = 0; i < 4; i++)
    t[ty + i * 8][tx] = src[(size_t)(k0 + ty + i * 8) * N + n0 + tx];
  __syncthreads();
#pragma unroll
  for (int i = 0; i < 4; i++)
    dst[(size_t)(n0 + ty + i * 8) * K + k0 + tx] = f2bf(t[tx][ty + i * 8]);
}

__global__ void concat_bias_kernel(const float* __restrict__ bq,
                                   const float* __restrict__ bk,
                                   const float* __restrict__ bv,
                                   float* __restrict__ out) {
  int i = blockIdx.x * 256 + threadIdx.x;
  if (i >= 3072) return;
  out[i] = (i < 2048) ? bq[i] : (i < 2560 ? bk[i - 2048] : bv[i - 2560]);
}

// V region of QKV -> Vt[b*512 + g*128 + d][2048 s], with kv-permutation c()
__global__ void transpose_v_kernel(const unsigned short* __restrict__ QKV,
                                   unsigned short* __restrict__ Vt) {
  __shared__ unsigned short t[32][33];
  const int tx = threadIdx.x, ty = threadIdx.y;
  const int c0 = blockIdx.x * 32;  // gd
  const int r0 = blockIdx.y * 32;  // b*2048+s
#pragma unroll
  for (int i = 0; i < 4; i++)
    t[ty + i * 8][tx] = QKV[(size_t)(r0 + ty + i * 8) * 3072 + 2560 + c0 + tx];
  __syncthreads();
#pragma unroll
  for (int i = 0; i < 4; i++) {
    const int gd = c0 + ty + i * 8;
    const int r = r0 + tx;
    const int b = r >> 11, s = r & 2047;
    const int sp = (s & ~63) | ((s & 12) << 1) | (((s >> 4) & 1) << 2) | (s & 3) | (s & 32);
    Vt[(size_t)(b * 512 + gd) * 2048 + sp] = t[tx][ty + i * 8];
  }
}

// ---------------------------------------------------------------------------
// Pipelined GEMM: C[m][n] = (sum_k A[m][k]*Bt[n][k] + bias[n]) * (n<qcols?qscale:1)
// Tile: (ARNDS*128) x (BRNDS*128), BK=32. 512 threads = 8 waves (2M x 4N).
// 4-buffer LDS ring, prefetch 2 K-tiles ahead, counted vmcnt, raw s_barrier.
// 64 B LDS rows -> frag reads are bank-conflict-free by construction.
template <int ARNDS, int BRNDS, bool BF16OUT>
__global__ __launch_bounds__(512, 2)
void gemm_pipe_kernel(const unsigned short* __restrict__ A,
                      const unsigned short* __restrict__ Bt,
                      const float* __restrict__ bias,
                      void* __restrict__ C, int M, int N, int K,
                      float qscale, int qcols) {
  constexpr int FM = ARNDS * 4;           // M-frags per wave
  constexpr int FN = BRNDS * 2;           // N-frags per wave
  constexpr int HFM = FM / 2;
  constexpr int BUFE = (ARNDS + BRNDS) * 4096;  // elems per ring buffer
  __shared__ unsigned short lds[4 * BUFE];

  const int tid = threadIdx.x;
  const int w = tid >> 6, l = tid & 63, lg = l >> 4, ll = l & 15;
  const int wm = w >> 2, wn = w & 3;
  const int m0 = blockIdx.y * (ARNDS * 128);
  const int n0 = blockIdx.x * (BRNDS * 128);
  const int NT = K >> 5;

  const f32x4 fz = {0.f, 0.f, 0.f, 0.f};
  f32x4 acc[FM][FN];
#pragma unroll
  for (int i = 0; i < FM; i++)
#pragma unroll
    for (int j = 0; j < FN; j++) acc[i][j] = fz;

  // staging: round r covers 128 rows; thread -> (row=tid>>2, 16B chunk=tid&3)
  const int srow = tid >> 2, schunk = tid & 3;
  const unsigned short* Ag = A + (size_t)(m0 + srow) * K + schunk * 8;
  const unsigned short* Bg = Bt + (size_t)(n0 + srow) * K + schunk * 8;

  auto stageA = [&](int t) {
    unsigned short* dst = &lds[(t & 3) * BUFE + tid * 8];
#pragma unroll
    for (int r = 0; r < ARNDS; ++r)
      gload_lds16(Ag + (size_t)(r * 128) * K + t * 32, dst + r * 4096);
  };
  auto stageB = [&](int t) {
    unsigned short* dst = &lds[(t & 3) * BUFE + ARNDS * 4096 + tid * 8];
#pragma unroll
    for (int r = 0; r < BRNDS; ++r)
      gload_lds16(Bg + (size_t)(r * 128) * K + t * 32, dst + r * 4096);
  };

  stageA(0); stageB(0);
  stageA(1); stageB(1);

  for (int t = 0; t < NT; ++t) {
    // tile t's (ARNDS+BRNDS) loads are the oldest; 2 newer tiles stay in flight
    if (t + 1 < NT) {
      if constexpr (ARNDS + BRNDS == 4)
        asm volatile("s_waitcnt vmcnt(4)" ::: "memory");
      else
        asm volatile("s_waitcnt vmcnt(3)" ::: "memory");
    } else {
      asm volatile("s_waitcnt vmcnt(0)" ::: "memory");
    }
    __builtin_amdgcn_s_barrier();
    const unsigned short* bufp = &lds[(t & 3) * BUFE];

    bf16x8 bfrag[FN], afrag[HFM];
#pragma unroll
    for (int ni = 0; ni < FN; ++ni)
      bfrag[ni] = *reinterpret_cast<const bf16x8*>(
          &bufp[ARNDS * 4096 + (wn * FN * 16 + ni * 16 + ll) * 32 + lg * 8]);
#pragma unroll
    for (int mi = 0; mi < HFM; ++mi)
      afrag[mi] = *reinterpret_cast<const bf16x8*>(
          &bufp[(wm * FM * 16 + mi * 16 + ll) * 32 + lg * 8]);
    if (t + 2 < NT) stageA(t + 2);
    __builtin_amdgcn_s_setprio(1);
#pragma unroll
    for (int mi = 0; mi < HFM; ++mi)
#pragma unroll
      for (int ni = 0; ni < FN; ++ni)
        acc[mi][ni] = MFMA_16x16x32(afrag[mi], bfrag[ni], acc[mi][ni]);
    __builtin_amdgcn_s_setprio(0);

#pragma unroll
    for (int mi = 0; mi < HFM; ++mi)
      afrag[mi] = *reinterpret_cast<const bf16x8*>(
          &bufp[(wm * FM * 16 + (HFM + mi) * 16 + ll) * 32 + lg * 8]);
    if (t + 2 < NT) stageB(t + 2);
    __builtin_amdgcn_s_setprio(1);
#pragma unroll
    for (int mi = 0; mi < HFM; ++mi)
#pragma unroll
      for (int ni = 0; ni < FN; ++ni)
        acc[HFM + mi][ni] = MFMA_16x16x32(afrag[mi], bfrag[ni], acc[HFM + mi][ni]);
    __builtin_amdgcn_s_setprio(0);
  }

  // epilogue
#pragma unroll
  for (int mi = 0; mi < FM; ++mi) {
#pragma unroll
    for (int ni = 0; ni < FN; ++ni) {
      const int gc = n0 + wn * FN * 16 + ni * 16 + ll;
      const float bv = bias[gc];
      const float sc = (gc < qcols) ? qscale : 1.0f;
#pragma unroll
      for (int r = 0; r < 4; ++r) {
        const int gr = m0 + wm * FM * 16 + mi * 16 + 4 * lg + r;
        const float v = (acc[mi][ni][r] + bv) * sc;
        if constexpr (BF16OUT)
          ((unsigned short*)C)[(size_t)gr * N + gc] = f2bf(v);
        else
          ((float*)C)[(size_t)gr * N + gc] = v;
      }
    }
  }
}

// ---------------------------------------------------------------------------
// Flash attention, swapped-QK^T structure (unchanged from R1).
__global__ __launch_bounds__(256, 2)
void attn_kernel(const unsigned short* __restrict__ QKV,
                 const unsigned short* __restrict__ Vt,
                 unsigned short* __restrict__ AO) {
  __shared__ unsigned short Klds[64 * 128];  // [kv][d]   elem ^ ((kv&7)<<3)
  __shared__ unsigned short Vlds[128 * 64];  // [d][c]    elem ^ ((d&7)<<3)

  const int tid = threadIdx.x;
  const int w = tid >> 6, l = tid & 63, lg = l >> 4, ll = l & 15;
  const int bh = blockIdx.y;
  const int b = bh >> 4, h = bh & 15, g = h >> 2;
  const int q0 = blockIdx.x * 128 + w * 32;
  const size_t row_base = (size_t)b * 2048 * 3072;
  const unsigned short* Vg = Vt + (size_t)(b * 512 + g * 128) * 2048;

  bf16x8 qf[2][4];
#pragma unroll
  for (int mi = 0; mi < 2; mi++)
#pragma unroll
    for (int ds = 0; ds < 4; ds++)
      qf[mi][ds] = *reinterpret_cast<const bf16x8*>(
          QKV + row_base + (size_t)(q0 + mi * 16 + ll) * 3072 + h * 128 + ds * 32 + 8 * lg);

  const f32x4 fz = {0.f, 0.f, 0.f, 0.f};
  f32x4 o[8][2];
#pragma unroll
  for (int di = 0; di < 8; di++)
#pragma unroll
    for (int mi = 0; mi < 2; mi++) o[di][mi] = fz;
  float m2[2] = {-3.0e38f, -3.0e38f}, lsum[2] = {0.f, 0.f};

  const int krow = tid >> 4, kc8 = tid & 15;
  const int vrow = tid >> 3, vc8 = tid & 7;
  const unsigned short* Kg = QKV + row_base + 2048 + g * 128 + kc8 * 8 + (size_t)krow * 3072;
  int klo[4], vlo[4];
#pragma unroll
  for (int i = 0; i < 4; i++) {
    const int kr = krow + 16 * i;
    klo[i] = (kr * 128 + kc8 * 8) ^ ((kr & 7) << 3);
    const int vr = vrow + 32 * i;
    vlo[i] = (vr * 64 + vc8 * 8) ^ ((vr & 7) << 3);
  }

  bf16x8 kreg[4], vreg[4];
#pragma unroll
  for (int i = 0; i < 4; i++) {
    kreg[i] = *reinterpret_cast<const bf16x8*>(Kg + (size_t)(16 * i) * 3072);
    vreg[i] = *reinterpret_cast<const bf16x8*>(Vg + (size_t)(vrow + 32 * i) * 2048 + vc8 * 8);
  }

  const float THR = 8.0f;

  for (int kt = 0; kt < 32; kt++) {
#pragma unroll
    for (int i = 0; i < 4; i++) *reinterpret_cast<bf16x8*>(&Klds[klo[i]]) = kreg[i];
#pragma unroll
    for (int i = 0; i < 4; i++) *reinterpret_cast<bf16x8*>(&Vlds[vlo[i]]) = vreg[i];
    __syncthreads();

    if (kt + 1 < 32) {
#pragma unroll
      for (int i = 0; i < 4; i++) {
        kreg[i] = *reinterpret_cast<const bf16x8*>(
            Kg + (size_t)((kt + 1) * 64 + 16 * i) * 3072);
        vreg[i] = *reinterpret_cast<const bf16x8*>(
            Vg + (size_t)(vrow + 32 * i) * 2048 + (kt + 1) * 64 + vc8 * 8);
      }
    }

    f32x4 st[4][2];
#pragma unroll
    for (int ni = 0; ni < 4; ni++)
#pragma unroll
      for (int mi = 0; mi < 2; mi++) st[ni][mi] = fz;
#pragma unroll
    for (int ds = 0; ds < 4; ds++) {
      bf16x8 kf[4];
#pragma unroll
      for (int ni = 0; ni < 4; ni++) {
        const int kr = ni * 16 + ll;
        kf[ni] = *reinterpret_cast<const bf16x8*>(
            &Klds[(kr * 128 + ds * 32 + 8 * lg) ^ ((kr & 7) << 3)]);
      }
#pragma unroll
      for (int ni = 0; ni < 4; ni++)
#pragma unroll
        for (int mi = 0; mi < 2; mi++)
          st[ni][mi] = MFMA_16x16x32(kf[ni], qf[mi][ds], st[ni][mi]);
    }

    float pm[2];
#pragma unroll
    for (int mi = 0; mi < 2; mi++) {
      float a0 = fmaxf(fmaxf(st[0][mi][0], st[0][mi][1]), fmaxf(st[0][mi][2], st[0][mi][3]));
      float a1 = fmaxf(fmaxf(st[1][mi][0], st[1][mi][1]), fmaxf(st[1][mi][2], st[1][mi][3]));
      float a2 = fmaxf(fmaxf(st[2][mi][0], st[2][mi][1]), fmaxf(st[2][mi][2], st[2][mi][3]));
      float a3 = fmaxf(fmaxf(st[3][mi][0], st[3][mi][1]), fmaxf(st[3][mi][2], st[3][mi][3]));
      pm[mi] = fmaxf(fmaxf(a0, a1), fmaxf(a2, a3));
      pm[mi] = fmaxf(pm[mi], __shfl_xor(pm[mi], 16, 64));
      pm[mi] = fmaxf(pm[mi], __shfl_xor(pm[mi], 32, 64));
    }
    const bool grow = (pm[0] > m2[0] + THR) || (pm[1] > m2[1] + THR);
    if (__any(grow)) {
#pragma unroll
      for (int mi = 0; mi < 2; mi++) {
        const float mn = fmaxf(m2[mi], pm[mi]);
        const float fac = __builtin_amdgcn_exp2f(m2[mi] - mn);
        m2[mi] = mn;
        lsum[mi] *= fac;
#pragma unroll
        for (int di = 0; di < 8; di++) o[di][mi] *= fac;
      }
    }
    float ps[2] = {0.f, 0.f};
#pragma unroll
    for (int ni = 0; ni < 4; ni++)
#pragma unroll
      for (int mi = 0; mi < 2; mi++)
#pragma unroll
        for (int r = 0; r < 4; r++) {
          const float pv = __builtin_amdgcn_exp2f(st[ni][mi][r] - m2[mi]);
          st[ni][mi][r] = pv;
          ps[mi] += pv;
        }
#pragma unroll
    for (int mi = 0; mi < 2; mi++) {
      ps[mi] += __shfl_xor(ps[mi], 16, 64);
      ps[mi] += __shfl_xor(ps[mi], 32, 64);
      lsum[mi] += ps[mi];
    }

    bf16x8 pf[2][2];
#pragma unroll
    for (int mi = 0; mi < 2; mi++)
#pragma unroll
      for (int ks = 0; ks < 2; ks++)
#pragma unroll
        for (int j = 0; j < 4; j++) {
          pf[mi][ks][j]     = (short)f2bf(st[2 * ks][mi][j]);
          pf[mi][ks][4 + j] = (short)f2bf(st[2 * ks + 1][mi][j]);
        }

#pragma unroll
    for (int ks = 0; ks < 2; ks++)
#pragma unroll
      for (int di = 0; di < 8; di++) {
        const int dr = di * 16 + ll;
        const bf16x8 vf = *reinterpret_cast<const bf16x8*>(
            &Vlds[(dr * 64 + ks * 32 + 8 * lg) ^ ((dr & 7) << 3)]);
#pragma unroll
        for (int mi = 0; mi < 2; mi++)
          o[di][mi] = MFMA_16x16x32(vf, pf[mi][ks], o[di][mi]);
      }
    __syncthreads();
  }

  float invl[2];
#pragma unroll
  for (int mi = 0; mi < 2; mi++) invl[mi] = 1.0f / lsum[mi];
#pragma unroll
  for (int mi = 0; mi < 2; mi++) {
    const size_t rowoff = (size_t)(b * 2048 + q0 + mi * 16 + ll) * 2048 + h * 128;
#pragma unroll
    for (int di = 0; di < 8; di++) {
      union { unsigned short s[4]; bf16x4 v; } ov;
#pragma unroll
      for (int r = 0; r < 4; r++) ov.s[r] = f2bf(o[di][mi][r] * invl[mi]);
      *reinterpret_cast<bf16x4*>(&AO[rowoff + di * 16 + 4 * lg]) = ov.v;
    }
  }
}

// ---------------------------------------------------------------------------
extern "C" void kernel_launch(void* const* d_in, const int* in_sizes, int n_in,
                              void* d_out, int out_size, void* d_ws, size_t ws_size,
                              hipStream_t stream) {
  const float* x  = (const float*)d_in[0];
  const float* Wq = (const float*)d_in[1];
  const float* bq = (const float*)d_in[2];
  const float* Wk = (const float*)d_in[3];
  const float* bk = (const float*)d_in[4];
  const float* Wv = (const float*)d_in[5];
  const float* bv = (const float*)d_in[6];
  const float* Wo = (const float*)d_in[7];
  const float* bo = (const float*)d_in[8];
  float* out = (float*)d_out;

  // workspace carve (bf16 elems):
  unsigned short* xb    = (unsigned short*)d_ws;               // 4096*2048
  unsigned short* Vt    = xb;                                   // alias: xb dead after QKV GEMM
  unsigned short* WqkvT = xb + (size_t)4096 * 2048;            // 3072*2048
  unsigned short* WoT   = WqkvT + (size_t)3072 * 2048;         // 2048*2048
  unsigned short* QKV   = WoT + (size_t)2048 * 2048;           // 4096*3072
  unsigned short* AO    = QKV + (size_t)4096 * 3072;           // 4096*2048
  float* bqkv = (float*)(AO + (size_t)4096 * 2048);            // 3072 f32

  const float QSC2 = 0.08838834764831845f * 1.4426950408889634f;  // 1/sqrt(D)*log2e

  cast_x_kernel<<<4096, 256, 0, stream>>>(x, xb, (long)8388608);
  transpose_cast_kernel<<<dim3(64, 64), dim3(32, 8), 0, stream>>>(Wq, WqkvT, 2048, 2048);
  transpose_cast_kernel<<<dim3(16, 64), dim3(32, 8), 0, stream>>>(Wk, WqkvT + (size_t)2048 * 2048, 2048, 512);
  transpose_cast_kernel<<<dim3(16, 64), dim3(32, 8), 0, stream>>>(Wv, WqkvT + (size_t)2560 * 2048, 2048, 512);
  transpose_cast_kernel<<<dim3(64, 64), dim3(32, 8), 0, stream>>>(Wo, WoT, 2048, 2048);
  concat_bias_kernel<<<12, 256, 0, stream>>>(bq, bk, bv, bqkv);

  // QKV = xb @ WqkvT^T + bqkv; Q columns pre-scaled by QSC2 -> bf16 [4096][3072]
  gemm_pipe_kernel<2, 2, true><<<dim3(12, 16), 512, 0, stream>>>(
      xb, WqkvT, bqkv, QKV, 4096, 3072, 2048, QSC2, 2048);
  // V^T (kv-permuted) -> Vt [1024][2048]  (overwrites xb, now dead)
  transpose_v_kernel<<<dim3(16, 128), dim3(32, 8), 0, stream>>>(QKV, Vt);
  // flash attention -> AO bf16 [4096][2048]
  attn_kernel<<<dim3(16, 32), 256, 0, stream>>>(QKV, Vt, AO);
  // out = AO @ WoT^T + bo -> fp32
  gemm_pipe_kernel<1, 2, false><<<dim3(8, 32), 512, 0, stream>>>(
      AO, WoT, bo, out, 4096, 2048, 2048, 1.0f, 0);
}

// Round 4
// 197.913 us; speedup vs baseline: 2.0007x; 1.0889x over previous
//
#include <hip/hip_runtime.h>
#include <hip/hip_bf16.h>

// ---------------------------------------------------------------------------
// GQA block: y = Attn(x Wq + bq, x Wk + bk, x Wv + bv) Wo + bo
// B=2 S=2048 E=2048 H=16 G=4 D=128 R=4.  All GEMMs in bf16 MFMA, fp32 accum.
// R1: swapped QK^T attention (P in-register), V pre-transpose, defer-max.
// R2: GEMM 8-wave pipeline, 4-deep LDS ring, counted vmcnt, raw s_barrier.
// R3: QKV GEMM 256x192 tile -> grid 256 (full CU coverage); attn K/V LDS
//     double-buffer (1 barrier/tile); HW bf16 cvt in attn hot path.
// ---------------------------------------------------------------------------

typedef __attribute__((ext_vector_type(8))) short bf16x8;
typedef __attribute__((ext_vector_type(4))) short bf16x4;
typedef __attribute__((ext_vector_type(4))) float f32x4;

#define MFMA_16x16x32(a, b, c) __builtin_amdgcn_mfma_f32_16x16x32_bf16((a), (b), (c), 0, 0, 0)

__device__ __forceinline__ unsigned short f2bf(float x) {
  union { float f; unsigned int u; } c;
  c.f = x;
  unsigned int u = c.u;
  return (unsigned short)((u + 0x7fffu + ((u >> 16) & 1u)) >> 16);  // RNE
}

__device__ __forceinline__ unsigned short f2bf_hw(float x) {
  __hip_bfloat16 h = __float2bfloat16(x);
  union { __hip_bfloat16 h; unsigned short u; } c;
  c.h = h;
  return c.u;
}

__device__ __forceinline__ void gload_lds16(const void* g, void* l) {
  __builtin_amdgcn_global_load_lds(
      (const __attribute__((address_space(1))) unsigned int*)g,
      (__attribute__((address_space(3))) unsigned int*)l, 16, 0, 0);
}

// ---------------------------------------------------------------------------
// cast fp32 -> bf16, 8 elems/thread
__global__ void cast_x_kernel(const float* __restrict__ x,
                              unsigned short* __restrict__ out, long n) {
  long i = ((long)blockIdx.x * blockDim.x + threadIdx.x) * 8;
  if (i >= n) return;
  float4 a = *reinterpret_cast<const float4*>(x + i);
  float4 b = *reinterpret_cast<const float4*>(x + i + 4);
  union { unsigned short s[8]; bf16x8 v; } o;
  o.s[0] = f2bf(a.x); o.s[1] = f2bf(a.y); o.s[2] = f2bf(a.z); o.s[3] = f2bf(a.w);
  o.s[4] = f2bf(b.x); o.s[5] = f2bf(b.y); o.s[6] = f2bf(b.z); o.s[7] = f2bf(b.w);
  *reinterpret_cast<bf16x8*>(out + i) = o.v;
}

// All four weight transposes in one launch.
// n-index 0..5119: [0,2048)=Wq, [2048,2560)=Wk, [2560,3072)=Wv -> WqkvT rows;
// [3072,5120) = Wo -> WoT rows.  All K=2048.
__global__ void prep_w_kernel(const float* __restrict__ Wq,
                              const float* __restrict__ Wk,
                              const float* __restrict__ Wv,
                              const float* __restrict__ Wo,
                              unsigned short* __restrict__ WqkvT,
                              unsigned short* __restrict__ WoT) {
  __shared__ float t[32][33];
  const int tx = threadIdx.x, ty = threadIdx.y;
  const int ng = blockIdx.x * 32;
  const int k0 = blockIdx.y * 32;
  const float* src;
  int srcN, n0;
  unsigned short* dst;
  if (ng < 2048)      { src = Wq; srcN = 2048; n0 = ng;        dst = WqkvT + (size_t)ng * 2048; }
  else if (ng < 2560) { src = Wk; srcN = 512;  n0 = ng - 2048; dst = WqkvT + (size_t)ng * 2048; }
  else if (ng < 3072) { src = Wv; srcN = 512;  n0 = ng - 2560; dst = WqkvT + (size_t)ng * 2048; }
  else                { src = Wo; srcN = 2048; n0 = ng - 3072; dst = WoT + (size_t)(ng - 3072) * 2048; }
#pragma unroll
  for (int i = 0; i < 4; i++)
    t[ty + i * 8][tx] = src[(size_t)(k0 + ty + i * 8) * srcN + n0 + tx];
  __syncthreads();
#pragma unroll
  for (int i = 0; i < 4; i++)
    dst[(size_t)(ty + i * 8) * 2048 + k0 + tx] = f2bf(t[tx][ty + i * 8]);
}

__global__ void concat_bias_kernel(const float* __restrict__ bq,
                                   const float* __restrict__ bk,
                                   const float* __restrict__ bv,
                                   float* __restrict__ out) {
  int i = blockIdx.x * 256 + threadIdx.x;
  if (i >= 3072) return;
  out[i] = (i < 2048) ? bq[i] : (i < 2560 ? bk[i - 2048] : bv[i - 2560]);
}

// V region of QKV -> Vt[b*512 + g*128 + d][2048 s], with kv-permutation c()
__global__ void transpose_v_kernel(const unsigned short* __restrict__ QKV,
                                   unsigned short* __restrict__ Vt) {
  __shared__ unsigned short t[32][33];
  const int tx = threadIdx.x, ty = threadIdx.y;
  const int c0 = blockIdx.x * 32;  // gd
  const int r0 = blockIdx.y * 32;  // b*2048+s
#pragma unroll
  for (int i = 0; i < 4; i++)
    t[ty + i * 8][tx] = QKV[(size_t)(r0 + ty + i * 8) * 3072 + 2560 + c0 + tx];
  __syncthreads();
#pragma unroll
  for (int i = 0; i < 4; i++) {
    const int gd = c0 + ty + i * 8;
    const int r = r0 + tx;
    const int b = r >> 11, s = r & 2047;
    const int sp = (s & ~63) | ((s & 12) << 1) | (((s >> 4) & 1) << 2) | (s & 3) | (s & 32);
    Vt[(size_t)(b * 512 + gd) * 2048 + sp] = t[tx][ty + i * 8];
  }
}

// ---------------------------------------------------------------------------
// Pipelined GEMM: C[m][n] = (sum_k A[m][k]*Bt[n][k] + bias[n]) * (n<qcols?qscale:1)
// Tile: AROWS x BROWS, BK=32. 512 threads = 8 waves (2M x 4N).
// 4-buffer LDS ring, prefetch 2 K-tiles ahead, counted vmcnt, raw s_barrier.
// Chunk-based staging: uniform LOADS gload_lds per thread (dummy chunks pad
// to keep per-wave vmcnt counts identical across all waves).
template <int AROWS, int BROWS, bool BF16OUT>
__global__ __launch_bounds__(512, 2)
void gemm_pipe_kernel(const unsigned short* __restrict__ A,
                      const unsigned short* __restrict__ Bt,
                      const float* __restrict__ bias,
                      void* __restrict__ C, int M, int N, int K,
                      float qscale, int qcols) {
  constexpr int FM = AROWS / 32;          // M-frags per wave (wm splits 2)
  constexpr int FN = BROWS / 64;          // N-frags per wave (wn splits 4)
  constexpr int HFM = FM / 2;
  constexpr int TC = (AROWS + BROWS) * 4; // real 16B chunks per K-tile
  constexpr int LOADS = (TC + 511) / 512; // gload_lds per thread per tile
  constexpr int PC = LOADS * 512;         // padded chunk count
  constexpr int BUFE = PC * 8;            // elems per ring buffer
  constexpr int BOFF = AROWS * 32;        // B region elem offset in buffer
  constexpr int LH = (LOADS + 1) / 2;
  __shared__ unsigned short lds[4 * BUFE];

  const int tid = threadIdx.x;
  const int w = tid >> 6, l = tid & 63, lg = l >> 4, ll = l & 15;
  const int wm = w >> 2, wn = w & 3;
  const int m0 = blockIdx.y * AROWS;
  const int n0 = blockIdx.x * BROWS;
  const int NT = K >> 5;

  const f32x4 fz = {0.f, 0.f, 0.f, 0.f};
  f32x4 acc[FM][FN];
#pragma unroll
  for (int i = 0; i < FM; i++)
#pragma unroll
    for (int j = 0; j < FN; j++) acc[i][j] = fz;

  // per-thread staging sources (advance by t*32 elems per K-tile)
  const unsigned short* gsrc[LOADS];
#pragma unroll
  for (int i = 0; i < LOADS; ++i) {
    const int c = tid + 512 * i;
    if (c < AROWS * 4) {
      gsrc[i] = A + (size_t)(m0 + (c >> 2)) * K + (c & 3) * 8;
    } else if (c < TC) {
      const int cb = c - AROWS * 4;
      gsrc[i] = Bt + (size_t)(n0 + (cb >> 2)) * K + (cb & 3) * 8;
    } else {
      gsrc[i] = Bt + (size_t)n0 * K;  // dummy, lands in pad region
    }
  }

  auto stage_lo = [&](int t) {
    unsigned short* dst = &lds[(t & 3) * BUFE + tid * 8];
#pragma unroll
    for (int i = 0; i < LH; ++i) gload_lds16(gsrc[i] + t * 32, dst + i * 4096);
  };
  auto stage_hi = [&](int t) {
    unsigned short* dst = &lds[(t & 3) * BUFE + tid * 8];
#pragma unroll
    for (int i = LH; i < LOADS; ++i) gload_lds16(gsrc[i] + t * 32, dst + i * 4096);
  };

  stage_lo(0); stage_hi(0);
  stage_lo(1); stage_hi(1);

  for (int t = 0; t < NT; ++t) {
    // tile t's LOADS are the oldest; tile t+1's LOADS stay in flight
    if (t + 1 < NT) {
      if constexpr (LOADS == 4)
        asm volatile("s_waitcnt vmcnt(4)" ::: "memory");
      else if constexpr (LOADS == 3)
        asm volatile("s_waitcnt vmcnt(3)" ::: "memory");
      else
        asm volatile("s_waitcnt vmcnt(0)" ::: "memory");
    } else {
      asm volatile("s_waitcnt vmcnt(0)" ::: "memory");
    }
    __builtin_amdgcn_s_barrier();
    const unsigned short* bufp = &lds[(t & 3) * BUFE];

    bf16x8 bfrag[FN], afrag[HFM];
#pragma unroll
    for (int ni = 0; ni < FN; ++ni)
      bfrag[ni] = *reinterpret_cast<const bf16x8*>(
          &bufp[BOFF + (wn * FN * 16 + ni * 16 + ll) * 32 + lg * 8]);
#pragma unroll
    for (int mi = 0; mi < HFM; ++mi)
      afrag[mi] = *reinterpret_cast<const bf16x8*>(
          &bufp[(wm * (AROWS / 2) + mi * 16 + ll) * 32 + lg * 8]);
    if (t + 2 < NT) stage_lo(t + 2);
    __builtin_amdgcn_s_setprio(1);
#pragma unroll
    for (int mi = 0; mi < HFM; ++mi)
#pragma unroll
      for (int ni = 0; ni < FN; ++ni)
        acc[mi][ni] = MFMA_16x16x32(afrag[mi], bfrag[ni], acc[mi][ni]);
    __builtin_amdgcn_s_setprio(0);

#pragma unroll
    for (int mi = 0; mi < HFM; ++mi)
      afrag[mi] = *reinterpret_cast<const bf16x8*>(
          &bufp[(wm * (AROWS / 2) + (HFM + mi) * 16 + ll) * 32 + lg * 8]);
    if (t + 2 < NT) stage_hi(t + 2);
    __builtin_amdgcn_s_setprio(1);
#pragma unroll
    for (int mi = 0; mi < HFM; ++mi)
#pragma unroll
      for (int ni = 0; ni < FN; ++ni)
        acc[HFM + mi][ni] = MFMA_16x16x32(afrag[mi], bfrag[ni], acc[HFM + mi][ni]);
    __builtin_amdgcn_s_setprio(0);
  }

  // epilogue
#pragma unroll
  for (int mi = 0; mi < FM; ++mi) {
#pragma unroll
    for (int ni = 0; ni < FN; ++ni) {
      const int gc = n0 + wn * FN * 16 + ni * 16 + ll;
      const float bv = bias[gc];
      const float sc = (gc < qcols) ? qscale : 1.0f;
#pragma unroll
      for (int r = 0; r < 4; ++r) {
        const int gr = m0 + wm * (AROWS / 2) + mi * 16 + 4 * lg + r;
        const float v = (acc[mi][ni][r] + bv) * sc;
        if constexpr (BF16OUT)
          ((unsigned short*)C)[(size_t)gr * N + gc] = f2bf(v);
        else
          ((float*)C)[(size_t)gr * N + gc] = v;
      }
    }
  }
}

// ---------------------------------------------------------------------------
// Flash attention, swapped-QK^T structure. K/V LDS double-buffered: one
// barrier per kv-tile (write buf[kt&1] -> sync -> compute; next iter writes
// the other buffer, so no trailing barrier needed).
__global__ __launch_bounds__(256, 2)
void attn_kernel(const unsigned short* __restrict__ QKV,
                 const unsigned short* __restrict__ Vt,
                 unsigned short* __restrict__ AO) {
  __shared__ unsigned short Klds[2][64 * 128];  // [kv][d]  elem ^ ((kv&7)<<3)
  __shared__ unsigned short Vlds[2][128 * 64];  // [d][c]   elem ^ ((d&7)<<3)

  const int tid = threadIdx.x;
  const int w = tid >> 6, l = tid & 63, lg = l >> 4, ll = l & 15;
  const int bh = blockIdx.y;
  const int b = bh >> 4, h = bh & 15, g = h >> 2;
  const int q0 = blockIdx.x * 128 + w * 32;
  const size_t row_base = (size_t)b * 2048 * 3072;
  const unsigned short* Vg = Vt + (size_t)(b * 512 + g * 128) * 2048;

  bf16x8 qf[2][4];
#pragma unroll
  for (int mi = 0; mi < 2; mi++)
#pragma unroll
    for (int ds = 0; ds < 4; ds++)
      qf[mi][ds] = *reinterpret_cast<const bf16x8*>(
          QKV + row_base + (size_t)(q0 + mi * 16 + ll) * 3072 + h * 128 + ds * 32 + 8 * lg);

  const f32x4 fz = {0.f, 0.f, 0.f, 0.f};
  f32x4 o[8][2];
#pragma unroll
  for (int di = 0; di < 8; di++)
#pragma unroll
    for (int mi = 0; mi < 2; mi++) o[di][mi] = fz;
  float m2[2] = {-3.0e38f, -3.0e38f}, lsum[2] = {0.f, 0.f};

  const int krow = tid >> 4, kc8 = tid & 15;
  const int vrow = tid >> 3, vc8 = tid & 7;
  const unsigned short* Kg = QKV + row_base + 2048 + g * 128 + kc8 * 8 + (size_t)krow * 3072;
  int klo[4], vlo[4];
#pragma unroll
  for (int i = 0; i < 4; i++) {
    const int kr = krow + 16 * i;
    klo[i] = (kr * 128 + kc8 * 8) ^ ((kr & 7) << 3);
    const int vr = vrow + 32 * i;
    vlo[i] = (vr * 64 + vc8 * 8) ^ ((vr & 7) << 3);
  }

  bf16x8 kreg[4], vreg[4];
#pragma unroll
  for (int i = 0; i < 4; i++) {
    kreg[i] = *reinterpret_cast<const bf16x8*>(Kg + (size_t)(16 * i) * 3072);
    vreg[i] = *reinterpret_cast<const bf16x8*>(Vg + (size_t)(vrow + 32 * i) * 2048 + vc8 * 8);
  }

  const float THR = 8.0f;

  for (int kt = 0; kt < 32; kt++) {
    const int cb = kt & 1;
#pragma unroll
    for (int i = 0; i < 4; i++) *reinterpret_cast<bf16x8*>(&Klds[cb][klo[i]]) = kreg[i];
#pragma unroll
    for (int i = 0; i < 4; i++) *reinterpret_cast<bf16x8*>(&Vlds[cb][vlo[i]]) = vreg[i];
    __syncthreads();

    if (kt + 1 < 32) {
#pragma unroll
      for (int i = 0; i < 4; i++) {
        kreg[i] = *reinterpret_cast<const bf16x8*>(
            Kg + (size_t)((kt + 1) * 64 + 16 * i) * 3072);
        vreg[i] = *reinterpret_cast<const bf16x8*>(
            Vg + (size_t)(vrow + 32 * i) * 2048 + (kt + 1) * 64 + vc8 * 8);
      }
    }

    f32x4 st[4][2];
#pragma unroll
    for (int ni = 0; ni < 4; ni++)
#pragma unroll
      for (int mi = 0; mi < 2; mi++) st[ni][mi] = fz;
#pragma unroll
    for (int ds = 0; ds < 4; ds++) {
      bf16x8 kf[4];
#pragma unroll
      for (int ni = 0; ni < 4; ni++) {
        const int kr = ni * 16 + ll;
        kf[ni] = *reinterpret_cast<const bf16x8*>(
            &Klds[cb][(kr * 128 + ds * 32 + 8 * lg) ^ ((kr & 7) << 3)]);
      }
#pragma unroll
      for (int ni = 0; ni < 4; ni++)
#pragma unroll
        for (int mi = 0; mi < 2; mi++)
          st[ni][mi] = MFMA_16x16x32(kf[ni], qf[mi][ds], st[ni][mi]);
    }

    float pm[2];
#pragma unroll
    for (int mi = 0; mi < 2; mi++) {
      float a0 = fmaxf(fmaxf(st[0][mi][0], st[0][mi][1]), st[0][mi][2]);
      float a1 = fmaxf(fmaxf(st[0][mi][3], st[1][mi][0]), st[1][mi][1]);
      float a2 = fmaxf(fmaxf(st[1][mi][2], st[1][mi][3]), st[2][mi][0]);
      float a3 = fmaxf(fmaxf(st[2][mi][1], st[2][mi][2]), st[2][mi][3]);
      float a4 = fmaxf(fmaxf(st[3][mi][0], st[3][mi][1]), st[3][mi][2]);
      pm[mi] = fmaxf(fmaxf(fmaxf(a0, a1), fmaxf(a2, a3)), fmaxf(a4, st[3][mi][3]));
      pm[mi] = fmaxf(pm[mi], __shfl_xor(pm[mi], 16, 64));
      pm[mi] = fmaxf(pm[mi], __shfl_xor(pm[mi], 32, 64));
    }
    const bool grow = (pm[0] > m2[0] + THR) || (pm[1] > m2[1] + THR);
    if (__any(grow)) {
#pragma unroll
      for (int mi = 0; mi < 2; mi++) {
        const float mn = fmaxf(m2[mi], pm[mi]);
        const float fac = __builtin_amdgcn_exp2f(m2[mi] - mn);
        m2[mi] = mn;
        lsum[mi] *= fac;
#pragma unroll
        for (int di = 0; di < 8; di++) o[di][mi] *= fac;
      }
    }
    float ps[2] = {0.f, 0.f};
#pragma unroll
    for (int ni = 0; ni < 4; ni++)
#pragma unroll
      for (int mi = 0; mi < 2; mi++)
#pragma unroll
        for (int r = 0; r < 4; r++) {
          const float pv = __builtin_amdgcn_exp2f(st[ni][mi][r] - m2[mi]);
          st[ni][mi][r] = pv;
          ps[mi] += pv;
        }
#pragma unroll
    for (int mi = 0; mi < 2; mi++) {
      ps[mi] += __shfl_xor(ps[mi], 16, 64);
      ps[mi] += __shfl_xor(ps[mi], 32, 64);
      lsum[mi] += ps[mi];
    }

    bf16x8 pf[2][2];
#pragma unroll
    for (int mi = 0; mi < 2; mi++)
#pragma unroll
      for (int ks = 0; ks < 2; ks++)
#pragma unroll
        for (int j = 0; j < 4; j++) {
          pf[mi][ks][j]     = (short)f2bf_hw(st[2 * ks][mi][j]);
          pf[mi][ks][4 + j] = (short)f2bf_hw(st[2 * ks + 1][mi][j]);
        }

#pragma unroll
    for (int ks = 0; ks < 2; ks++)
#pragma unroll
      for (int di = 0; di < 8; di++) {
        const int dr = di * 16 + ll;
        const bf16x8 vf = *reinterpret_cast<const bf16x8*>(
            &Vlds[cb][(dr * 64 + ks * 32 + 8 * lg) ^ ((dr & 7) << 3)]);
#pragma unroll
        for (int mi = 0; mi < 2; mi++)
          o[di][mi] = MFMA_16x16x32(vf, pf[mi][ks], o[di][mi]);
      }
  }

  float invl[2];
#pragma unroll
  for (int mi = 0; mi < 2; mi++) invl[mi] = 1.0f / lsum[mi];
#pragma unroll
  for (int mi = 0; mi < 2; mi++) {
    const size_t rowoff = (size_t)(b * 2048 + q0 + mi * 16 + ll) * 2048 + h * 128;
#pragma unroll
    for (int di = 0; di < 8; di++) {
      union { unsigned short s[4]; bf16x4 v; } ov;
#pragma unroll
      for (int r = 0; r < 4; r++) ov.s[r] = f2bf_hw(o[di][mi][r] * invl[mi]);
      *reinterpret_cast<bf16x4*>(&AO[rowoff + di * 16 + 4 * lg]) = ov.v;
    }
  }
}

// ---------------------------------------------------------------------------
extern "C" void kernel_launch(void* const* d_in, const int* in_sizes, int n_in,
                              void* d_out, int out_size, void* d_ws, size_t ws_size,
                              hipStream_t stream) {
  const float* x  = (const float*)d_in[0];
  const float* Wq = (const float*)d_in[1];
  const float* bq = (const float*)d_in[2];
  const float* Wk = (const float*)d_in[3];
  const float* bk = (const float*)d_in[4];
  const float* Wv = (const float*)d_in[5];
  const float* bv = (const float*)d_in[6];
  const float* Wo = (const float*)d_in[7];
  const float* bo = (const float*)d_in[8];
  float* out = (float*)d_out;

  // workspace carve (bf16 elems):
  unsigned short* xb    = (unsigned short*)d_ws;               // 4096*2048
  unsigned short* Vt    = xb;                                   // alias: xb dead after QKV GEMM
  unsigned short* WqkvT = xb + (size_t)4096 * 2048;            // 3072*2048
  unsigned short* WoT   = WqkvT + (size_t)3072 * 2048;         // 2048*2048
  unsigned short* QKV   = WoT + (size_t)2048 * 2048;           // 4096*3072
  unsigned short* AO    = QKV + (size_t)4096 * 3072;           // 4096*2048
  float* bqkv = (float*)(AO + (size_t)4096 * 2048);            // 3072 f32

  const float QSC2 = 0.08838834764831845f * 1.4426950408889634f;  // 1/sqrt(D)*log2e

  cast_x_kernel<<<4096, 256, 0, stream>>>(x, xb, (long)8388608);
  prep_w_kernel<<<dim3(160, 64), dim3(32, 8), 0, stream>>>(Wq, Wk, Wv, Wo, WqkvT, WoT);
  concat_bias_kernel<<<12, 256, 0, stream>>>(bq, bk, bv, bqkv);

  // QKV = xb @ WqkvT^T + bqkv; Q columns pre-scaled by QSC2 -> bf16 [4096][3072]
  gemm_pipe_kernel<256, 192, true><<<dim3(16, 16), 512, 0, stream>>>(
      xb, WqkvT, bqkv, QKV, 4096, 3072, 2048, QSC2, 2048);
  // V^T (kv-permuted) -> Vt [1024][2048]  (overwrites xb, now dead)
  transpose_v_kernel<<<dim3(16, 128), dim3(32, 8), 0, stream>>>(QKV, Vt);
  // flash attention -> AO bf16 [4096][2048]
  attn_kernel<<<dim3(16, 32), 256, 0, stream>>>(QKV, Vt, AO);
  // out = AO @ WoT^T + bo -> fp32
  gemm_pipe_kernel<128, 256, false><<<dim3(8, 32), 512, 0, stream>>>(
      AO, WoT, bo, out, 4096, 2048, 2048, 1.0f, 0);
}